// Round 7
// baseline (237.956 us; speedup 1.0000x reference)
//
#include <hip/hip_runtime.h>
#include <stdint.h>

// Depthwise causal conv1d, channel-last. x:(B,L,D) f32, w:(K,1,D), b:(D), y:(B,L,D).
// y[n,l,d] = sum_k w[k,d]*x[n,l+k-3,d] + b[d], zero-padded left.
//
// R11 == R10 resubmitted (broker infra failure; kernel never reached HW --
// same flake hit R7/R8, and the identical R9 source ran fine on retry).
//
// R10: global_load_lds ping-pong ring + high occupancy, zero barriers.
// R9 post-mortem: VGPR=40 proves the register ring was collapsed -- the
// compiler sank VGPR-destination loads to their uses (minimal live ranges),
// serializing HBM latency (6000 cyc/iter). Same as the R3 lesson. The only
// unsinkable staging primitive is global_load_lds (no destination register).
// R6 post-mortem: global_load_lds ring worked but 64 KB LDS -> 2 blocks/CU
// killed occupancy. This round combines both fixes:
//   - wave-private 8-row (8 KB) ping-pong ring -> 32 KB/block -> 4-5 blocks/CU
//   - CROWS=4: compute half A while loads fill half B; counted vmcnt(8)
//     leaves stores(c-1) + loads(c+1) in flight, never drains to 0
//   - halo carried in registers (loaded once as VGPR loads in prologue)
//   - zero barriers: producer == consumer wave
// FIFO per iteration c: [loads(c):4][stores(c-1):4][loads(c+1):4]
//   -> wait for loads(c) = vmcnt(8)  (vmcnt(4) at c=0 and c=NCH-1 edges).

#define CB 4
#define CL 4096
#define CD 2048
#define STRIP 256                // floats per channel strip (1 KB per row)
#define SF4 (STRIP / 4)          // 64 float4 per row-strip
#define HALO 3
#define RW 8                     // ring rows per wave (8 KB, two 4-row halves)
#define CROWS 4                  // rows per chunk
#define WROWS 32                 // rows per wave
#define NCH (WROWS / CROWS)      // 8 chunks per wave
#define BROWS (WROWS * 4)        // 128 rows per block (4 waves)
#define NSTRIP (CD / STRIP)      // 8
#define NSEG (CL / BROWS)        // 32

typedef float nfloat4 __attribute__((ext_vector_type(4)));

__global__ __launch_bounds__(256, 4) void short_conv_kernel(
    const float* __restrict__ x,
    const float* __restrict__ w,
    const float* __restrict__ bias,
    float* __restrict__ y)
{
    __shared__ __align__(16) float lds[4 * RW * STRIP];   // 32 KB -> 4-5 blocks/CU

    const int tid  = threadIdx.x;
    const int lane = tid & 63;
    const int wv   = tid >> 6;

    const int bid   = blockIdx.x;
    const int strip = bid & (NSTRIP - 1);
    const int seg   = (bid >> 3) & (NSEG - 1);
    const int b     = bid >> 8;

    const int lw0 = seg * BROWS + wv * WROWS;  // first output row of this wave
    const int c0  = strip * STRIP;

    const float* xs = x + (size_t)b * CL * CD + c0;            // row base
    float*       ys = y + (size_t)b * CL * CD + c0 + lane * 4; // lane-adjusted

    float* ldsw = lds + wv * RW * STRIP;       // wave-private 8-row ring

    // ---- Per-lane weights/bias (L2-resident, tiny), pinned before staging. ----
    const float4 w0 = *(const float4*)(w + 0 * CD + c0 + lane * 4);
    const float4 w1 = *(const float4*)(w + 1 * CD + c0 + lane * 4);
    const float4 w2 = *(const float4*)(w + 2 * CD + c0 + lane * 4);
    const float4 w3 = *(const float4*)(w + 3 * CD + c0 + lane * 4);
    const float4 bv = *(const float4*)(bias + c0 + lane * 4);

    // ---- Halo rows straight to VGPRs (one-time). ----
    float4 xm3, xm2, xm1;
    if (lw0 > 0) {
        xm3 = *(const float4*)(xs + (size_t)(lw0 - 3) * CD + lane * 4);
        xm2 = *(const float4*)(xs + (size_t)(lw0 - 2) * CD + lane * 4);
        xm1 = *(const float4*)(xs + (size_t)(lw0 - 1) * CD + lane * 4);
    } else {
        xm3 = xm2 = xm1 = make_float4(0.f, 0.f, 0.f, 0.f);
    }
    __builtin_amdgcn_sched_barrier(0);

    // ---- loads(0): rows lw0..lw0+3 -> slots 0..3 (lw0 % 8 == 0). ----
#pragma unroll
    for (int r = 0; r < CROWS; ++r) {
        const float* gsrc = xs + (size_t)(lw0 + r) * CD + lane * 4;
        float* ldst = &ldsw[r * STRIP + lane * 4];
        __builtin_amdgcn_global_load_lds(
            (const __attribute__((address_space(1))) uint32_t*)gsrc,
            (__attribute__((address_space(3))) uint32_t*)ldst,
            16, 0, 0);
    }
    __builtin_amdgcn_sched_barrier(0);

    const float4* lrow = (const float4*)ldsw + lane;   // ring row stride SF4

    // ---- Main loop, fully unrolled: all ring slots static. ----
#pragma unroll
    for (int c = 0; c < NCH; ++c) {
        const int lc = lw0 + c * CROWS;

        // Issue loads(c+1) into the other 4-row half (slots disjoint from
        // this chunk's compute slots).
        if (c + 1 < NCH) {
#pragma unroll
            for (int r = 0; r < CROWS; ++r) {
                const int l = lc + CROWS + r;          // wave-uniform
                const float* gsrc = xs + (size_t)l * CD + lane * 4;
                float* ldst = &ldsw[(l & (RW - 1)) * STRIP + lane * 4];
                __builtin_amdgcn_global_load_lds(
                    (const __attribute__((address_space(1))) uint32_t*)gsrc,
                    (__attribute__((address_space(3))) uint32_t*)ldst,
                    16, 0, 0);
            }
        }
        __builtin_amdgcn_sched_barrier(0);

        // Wait for loads(c) only; stores(c-1) + loads(c+1) stay in flight.
        if (c == 0 || c + 1 == NCH) {
            asm volatile("s_waitcnt vmcnt(4)" ::: "memory");
        } else {
            asm volatile("s_waitcnt vmcnt(8)" ::: "memory");
        }
        __builtin_amdgcn_sched_barrier(0);

        // ---- Compute 4 rows with register sliding window. ----
#pragma unroll
        for (int t = 0; t < CROWS; ++t) {
            const int l = lc + t;
            const float4 a0 = lrow[((c * CROWS + t) & (RW - 1)) * SF4];

            nfloat4 r;
            r.x = fmaf(w0.x, xm3.x, fmaf(w1.x, xm2.x, fmaf(w2.x, xm1.x, fmaf(w3.x, a0.x, bv.x))));
            r.y = fmaf(w0.y, xm3.y, fmaf(w1.y, xm2.y, fmaf(w2.y, xm1.y, fmaf(w3.y, a0.y, bv.y))));
            r.z = fmaf(w0.z, xm3.z, fmaf(w1.z, xm2.z, fmaf(w2.z, xm1.z, fmaf(w3.z, a0.z, bv.z))));
            r.w = fmaf(w0.w, xm3.w, fmaf(w1.w, xm2.w, fmaf(w2.w, xm1.w, fmaf(w3.w, a0.w, bv.w))));

            __builtin_nontemporal_store(r, (nfloat4*)(ys + (size_t)l * CD));

            xm3 = xm2;
            xm2 = xm1;
            xm1 = a0;
        }
    }
}

extern "C" void kernel_launch(void* const* d_in, const int* in_sizes, int n_in,
                              void* d_out, int out_size, void* d_ws, size_t ws_size,
                              hipStream_t stream) {
    const float* x = (const float*)d_in[0];
    const float* w = (const float*)d_in[1];
    const float* b = (const float*)d_in[2];
    float* y = (float*)d_out;

    const int grid = CB * NSTRIP * NSEG;   // 4 * 8 * 32 = 1024 blocks, 4/CU
    short_conv_kernel<<<grid, 256, 0, stream>>>(x, w, b, y);
}